// Round 6
// baseline (75.324 us; speedup 1.0000x reference)
//
#include <hip/hip_runtime.h>

// BipolarMorphological2D SMorph:
//   out[b,o,s] = exp(sm(p1,k1)) - exp(sm(p1,k2)) - exp(sm(p2,k1)) + exp(sm(p2,k2)) + bias[o]
// with sm = sum(z*e^z)/sum(e^z), z = log(max(+/-x,0.1)) + kf[p,o].
// Factorization: e^z = m * e^kf ; z*e^z = (m*lm)*e^kf + m*(kf*e^kf)
// -> fp32 pk-FMA reductions over P=288, no transcendentals in the hot loop.
//
// R6: kill the SMEM (s_load) A-path — R4/R5's hidden serializer (32 s_loads/
// phase need 128 SGPRs to hoist -> compiler chunks + drains lgkmcnt ~200cyc
// every few FMAs). New: grid = (8 wo-tiles, 30 ho, 4 b); block stages its
// 3x6-pixel A window (576 float4 = 9.2KB) into LDS once; inner loop reads A
// via broadcast ds_read_b128 with immediate offsets (lgkm domain = LDS only),
// B streams from L2 via coalesced global loads (vmcnt domain), 9 phases fully
// unrolled. Combine tree reuses the same 16KB LDS after a barrier.

typedef float v2f __attribute__((ext_vector_type(2)));

#define BB   4
#define CC   32
#define HH   32
#define WW   32
#define OO   64
#define HO   30
#define WO   30
#define NSP  (HO*WO)   // 900

// ---- prep: A[b,h,w,c] = (mp, mn, mp*log mp, mn*log mn)
//            Bm[ij,c,o] = (e^k1, k1*e^k1, e^k2, k2*e^k2)
__global__ __launch_bounds__(256) void smorph_prep(
    const float* __restrict__ x, const float* __restrict__ k1,
    const float* __restrict__ k2, float4* __restrict__ A, float4* __restrict__ Bm)
{
    int t = blockIdx.x * 256 + threadIdx.x;
    if (t < BB*CC*HH*WW) {
        float v = x[t];
        int b = t >> 15, c = (t >> 10) & 31, h = (t >> 5) & 31, w = t & 31;
        float mp = fmaxf(v, 0.1f), mn = fmaxf(-v, 0.1f);
        A[((b*HH + h)*WW + w)*CC + c] =
            make_float4(mp, mn, mp*logf(mp), mn*logf(mn));
    }
    if (t < 9*CC*OO) {
        float a = k1[t], bb = k2[t];
        float e1 = expf(a), e2 = expf(bb);
        Bm[t] = make_float4(e1, a*e1, e2, bb*e2);
    }
}

// grid (8, 30, 4): x = wo-tile (4 positions), y = ho, z = b. 4 waves/block.
__global__ __launch_bounds__(256, 4) void smorph_main(
    const float4* __restrict__ A, const float4* __restrict__ Bm,
    const float* __restrict__ bias, float* __restrict__ out)
{
    __shared__ __align__(16) char ldsbuf[16384];
    float4* ldsA = (float4*)ldsbuf;   // [pix 0..17][c 0..31], 9216 B (staging)
    v2f*    ldsr = (v2f*)ldsbuf;      // combine scratch view (16 KB)

    const int tid = threadIdx.x;
    const int o   = tid & 63;
    const int kq  = __builtin_amdgcn_readfirstlane(tid >> 6);  // wave 0..3
    const int w0  = blockIdx.x * 4;
    const int ho  = blockIdx.y;
    const int b   = blockIdx.z;

    // ---- stage A window: rows ho..ho+2, cols w0..w0+5 (clamped), all 32 c
    for (int u = tid; u < 18*CC; u += 256) {
        int c = u & 31, pix = u >> 5;         // pix = r*6 + wp
        int r = pix / 6, wp = pix - 6*r;
        int w = w0 + wp; if (w > WW-1) w = WW-1;
        ldsA[u] = A[((b*HH + ho + r)*WW + w)*CC + c];
    }
    __syncthreads();

    v2f P1d[4] = {}, P1n[4] = {}, P2d[4] = {}, P2n[4] = {};

    const float4* Bq = Bm + kq*8*OO + o;      // lane-coalesced B base
    const int lb = kq*8;                      // LDS c-offset of this wave

#pragma unroll
    for (int ij = 0; ij < 9; ++ij) {
        const int i = ij/3, j = ij - 3*(ij/3);

        float4 Bv[8];                          // coalesced global (vmcnt), L2-hit
#pragma unroll
        for (int c = 0; c < 8; ++c) Bv[c] = Bq[ij*(CC*OO) + c*OO];

#pragma unroll
        for (int t = 0; t < 4; ++t) {
            const int pb = (i*6 + t + j)*CC + lb;   // imm-offset ds_read base
#pragma unroll
            for (int c = 0; c < 8; ++c) {
                float4 Av = ldsA[pb + c];      // broadcast ds_read_b128
                v2f a1 = {Av.x, Av.y};         // (mp, mn)
                v2f a2 = {Av.z, Av.w};         // (mp*lmp, mn*lmn)
                v2f be1 = {Bv[c].x, Bv[c].x}, bk1 = {Bv[c].y, Bv[c].y};
                v2f be2 = {Bv[c].z, Bv[c].z}, bk2 = {Bv[c].w, Bv[c].w};
                P1d[t] += a1 * be1;
                P1n[t] += a2 * be1;
                P1n[t] += a1 * bk1;
                P2d[t] += a1 * be2;
                P2n[t] += a2 * be2;
                P2n[t] += a1 * bk2;
            }
        }
    }

    __syncthreads();   // A-staging reads done; LDS reused for combine

    // ---- combine K-split partials across the 4 waves (2-step tree)
    if (kq >= 2) {
        v2f* dst = ldsr + (kq - 2)*1024 + o;
#pragma unroll
        for (int t = 0; t < 4; ++t) {
            dst[(t*4+0)*64] = P1d[t];
            dst[(t*4+1)*64] = P1n[t];
            dst[(t*4+2)*64] = P2d[t];
            dst[(t*4+3)*64] = P2n[t];
        }
    }
    __syncthreads();
    if (kq < 2) {
        const v2f* srcp = ldsr + kq*1024 + o;
#pragma unroll
        for (int t = 0; t < 4; ++t) {
            P1d[t] += srcp[(t*4+0)*64];
            P1n[t] += srcp[(t*4+1)*64];
            P2d[t] += srcp[(t*4+2)*64];
            P2n[t] += srcp[(t*4+3)*64];
        }
    }
    __syncthreads();
    if (kq == 1) {
        v2f* dst = ldsr + o;
#pragma unroll
        for (int t = 0; t < 4; ++t) {
            dst[(t*4+0)*64] = P1d[t];
            dst[(t*4+1)*64] = P1n[t];
            dst[(t*4+2)*64] = P2d[t];
            dst[(t*4+3)*64] = P2n[t];
        }
    }
    __syncthreads();
    if (kq == 0) {
        const v2f* srcp = ldsr + o;
        const float bo = bias[o];
#pragma unroll
        for (int t = 0; t < 4; ++t) {
            v2f d1 = P1d[t] + srcp[(t*4+0)*64];
            v2f n1 = P1n[t] + srcp[(t*4+1)*64];
            v2f d2 = P2d[t] + srcp[(t*4+2)*64];
            v2f n2 = P2n[t] + srcp[(t*4+3)*64];
            int wo = w0 + t;
            if (wo < WO) {
                float r = expf(n1.x/d1.x) - expf(n2.x/d2.x)
                        - expf(n1.y/d1.y) + expf(n2.y/d2.y) + bo;
                out[(size_t)(b*OO + o)*NSP + ho*WO + wo] = r;
            }
        }
    }
}

extern "C" void kernel_launch(void* const* d_in, const int* in_sizes, int n_in,
                              void* d_out, int out_size, void* d_ws, size_t ws_size,
                              hipStream_t stream) {
    const float* x    = (const float*)d_in[0];
    const float* k1   = (const float*)d_in[1];
    const float* k2   = (const float*)d_in[2];
    const float* bias = (const float*)d_in[3];

    float4* A  = (float4*)d_ws;                                   // 2 MB
    float4* Bm = (float4*)((char*)d_ws + (size_t)BB*HH*WW*CC*16); // 294 KB
    float*  out = (float*)d_out;

    hipLaunchKernelGGL(smorph_prep, dim3((BB*CC*HH*WW + 255)/256), dim3(256), 0, stream,
                       x, k1, k2, A, Bm);

    hipLaunchKernelGGL(smorph_main, dim3((WO + 3)/4, HO, BB), dim3(256), 0, stream,
                       A, Bm, bias, out);
}

// Round 7
// 54.305 us; speedup vs baseline: 1.3870x; 1.3870x over previous
//
#include <hip/hip_runtime.h>

// BipolarMorphological2D SMorph:
//   out[b,o,s] = exp(sm(p1,k1)) - exp(sm(p1,k2)) - exp(sm(p2,k1)) + exp(sm(p2,k2)) + bias[o]
// with sm = sum(z*e^z)/sum(e^z), z = log(max(+/-x,0.1)) + kf[p,o].
// Factorization: e^z = m * e^kf ; z*e^z = (m*lm)*e^kf + m*(kf*e^kf)
// -> fp32 pk-FMA reductions over P=288, no transcendentals in the hot loop.
//
// R7 = R4 structure (900x4 blocks, 4 waves: kq = c-quarter, SREG=4 spatial,
// B coalesced from L2, LDS combine tree) with ONE change: the wave-uniform A
// loads are forced onto the VMEM pipe (in-order, vmcnt-counted, pipelineable)
// instead of SMEM s_load (out-of-order -> full lgkmcnt(0) drains, the R4/R5
// serializer) by laundering the A base pointer through an opaque "+v" asm.
// A uniform-address global_load_dwordx4 coalesces to one 16-B line request.

typedef float v2f __attribute__((ext_vector_type(2)));

#define BB   4
#define CC   32
#define HH   32
#define WW   32
#define OO   64
#define HO   30
#define WO   30
#define NSP  (HO*WO)   // 900 = 4*225, no tail

// ---- prep: A[b,h,w,c] = (mp, mn, mp*log mp, mn*log mn)
//            Bm[ij,c,o] = (e^k1, k1*e^k1, e^k2, k2*e^k2)
__global__ __launch_bounds__(256) void smorph_prep(
    const float* __restrict__ x, const float* __restrict__ k1,
    const float* __restrict__ k2, float4* __restrict__ A, float4* __restrict__ Bm)
{
    int t = blockIdx.x * 256 + threadIdx.x;
    if (t < BB*CC*HH*WW) {
        float v = x[t];
        int b = t >> 15, c = (t >> 10) & 31, h = (t >> 5) & 31, w = t & 31;
        float mp = fmaxf(v, 0.1f), mn = fmaxf(-v, 0.1f);
        A[((b*HH + h)*WW + w)*CC + c] =
            make_float4(mp, mn, mp*logf(mp), mn*logf(mn));
    }
    if (t < 9*CC*OO) {
        float a = k1[t], bb = k2[t];
        float e1 = expf(a), e2 = expf(bb);
        Bm[t] = make_float4(e1, a*e1, e2, bb*e2);
    }
}

// Opaque pass-through that pins the pointer in a VGPR pair: the compiler can
// no longer prove it uniform, so dependent loads stay on the VMEM pipe.
__device__ __forceinline__ const float4* as_vgpr(const float4* p) {
    asm("" : "+v"(p));
    return p;
}

__global__ __launch_bounds__(256, 4) void smorph_main(
    const float4* __restrict__ A, const float4* __restrict__ Bm,
    const float* __restrict__ bias, float* __restrict__ out)
{
    __shared__ v2f ldsr[2*16*64];   // 16 KB combine scratch (used only at end)

    const int tid = threadIdx.x;
    const int o   = tid & 63;
    const int kq  = __builtin_amdgcn_readfirstlane(tid >> 6);  // wave 0..3
    const int b   = blockIdx.y;
    const int s0  = blockIdx.x * 4;

    int abase[4];                   // float4 index of pixel (b,ho,wo), c = kq*8
#pragma unroll
    for (int t = 0; t < 4; ++t) {
        int s = s0 + t;
        int ho = s / WO, wo = s - ho*WO;
        abase[t] = ((b*HH + ho)*WW + wo)*CC + kq*8;
    }

    v2f P1d[4] = {}, P1n[4] = {}, P2d[4] = {}, P2n[4] = {};

    const float4* Bq = Bm + kq*8*OO + o;     // lane-coalesced B base (VMEM)
    const float4* Af = as_vgpr(A);           // uniform A -> VMEM, not SMEM

#pragma unroll
    for (int ij = 0; ij < 9; ++ij) {
        const int i = ij/3, j = ij - 3*(ij/3);

        float4 Bv[8];                        // coalesced global, L2-hit
#pragma unroll
        for (int c = 0; c < 8; ++c) Bv[c] = Bq[ij*(CC*OO) + c*OO];

#pragma unroll
        for (int t = 0; t < 4; ++t) {
            const float4* Ap = Af + (abase[t] + (i*WW + j)*CC);
#pragma unroll
            for (int c = 0; c < 8; ++c) {
                float4 Av = Ap[c];           // uniform-addr global_load_dwordx4
                v2f a1 = {Av.x, Av.y};       // (mp, mn)
                v2f a2 = {Av.z, Av.w};       // (mp*lmp, mn*lmn)
                v2f be1 = {Bv[c].x, Bv[c].x}, bk1 = {Bv[c].y, Bv[c].y};
                v2f be2 = {Bv[c].z, Bv[c].z}, bk2 = {Bv[c].w, Bv[c].w};
                P1d[t] += a1 * be1;
                P1n[t] += a2 * be1;
                P1n[t] += a1 * bk1;
                P2d[t] += a1 * be2;
                P2n[t] += a2 * be2;
                P2n[t] += a1 * bk2;
            }
        }
    }

    // ---- combine K-split partials across the 4 waves (2-step tree)
    if (kq >= 2) {
        v2f* dst = ldsr + (kq - 2)*1024 + o;
#pragma unroll
        for (int t = 0; t < 4; ++t) {
            dst[(t*4+0)*64] = P1d[t];
            dst[(t*4+1)*64] = P1n[t];
            dst[(t*4+2)*64] = P2d[t];
            dst[(t*4+3)*64] = P2n[t];
        }
    }
    __syncthreads();
    if (kq < 2) {
        const v2f* srcp = ldsr + kq*1024 + o;
#pragma unroll
        for (int t = 0; t < 4; ++t) {
            P1d[t] += srcp[(t*4+0)*64];
            P1n[t] += srcp[(t*4+1)*64];
            P2d[t] += srcp[(t*4+2)*64];
            P2n[t] += srcp[(t*4+3)*64];
        }
    }
    __syncthreads();
    if (kq == 1) {
        v2f* dst = ldsr + o;
#pragma unroll
        for (int t = 0; t < 4; ++t) {
            dst[(t*4+0)*64] = P1d[t];
            dst[(t*4+1)*64] = P1n[t];
            dst[(t*4+2)*64] = P2d[t];
            dst[(t*4+3)*64] = P2n[t];
        }
    }
    __syncthreads();
    if (kq == 0) {
        const v2f* srcp = ldsr + o;
        const float bo = bias[o];
#pragma unroll
        for (int t = 0; t < 4; ++t) {
            v2f d1 = P1d[t] + srcp[(t*4+0)*64];
            v2f n1 = P1n[t] + srcp[(t*4+1)*64];
            v2f d2 = P2d[t] + srcp[(t*4+2)*64];
            v2f n2 = P2n[t] + srcp[(t*4+3)*64];
            float r = expf(n1.x/d1.x) - expf(n2.x/d2.x)
                    - expf(n1.y/d1.y) + expf(n2.y/d2.y) + bo;
            out[(size_t)(b*OO + o)*NSP + (s0 + t)] = r;
        }
    }
}

extern "C" void kernel_launch(void* const* d_in, const int* in_sizes, int n_in,
                              void* d_out, int out_size, void* d_ws, size_t ws_size,
                              hipStream_t stream) {
    const float* x    = (const float*)d_in[0];
    const float* k1   = (const float*)d_in[1];
    const float* k2   = (const float*)d_in[2];
    const float* bias = (const float*)d_in[3];

    float4* A  = (float4*)d_ws;                                   // 2 MB
    float4* Bm = (float4*)((char*)d_ws + (size_t)BB*HH*WW*CC*16); // 294 KB
    float*  out = (float*)d_out;

    hipLaunchKernelGGL(smorph_prep, dim3((BB*CC*HH*WW + 255)/256), dim3(256), 0, stream,
                       x, k1, k2, A, Bm);

    hipLaunchKernelGGL(smorph_main, dim3(NSP/4, BB), dim3(256), 0, stream,
                       A, Bm, bias, out);
}

// Round 8
// 33.070 us; speedup vs baseline: 2.2777x; 1.6422x over previous
//
#include <hip/hip_runtime.h>

// BipolarMorphological2D SMorph:
//   out[b,o,s] = exp(sm(p1,k1)) - exp(sm(p1,k2)) - exp(sm(p2,k1)) + exp(sm(p2,k2)) + bias[o]
// with sm = sum(z*e^z)/sum(e^z), z = log(max(+/-x,0.1)) + kf[p,o].
// Factorization: e^z = m * e^kf ; z*e^z = (m*lm)*e^kf + m*(kf*e^kf)
// -> fp32 pk-FMA reductions over P=288, no transcendentals in the hot loop.
//
// R8: TLP doubling. All R2-R7 variants ran ~3.5 waves/SIMD (900ish blocks x 4
// waves) and plateaued at VALUBusy <=29% with zero LDS/HBM pressure -> pure
// exposed latency. R8 keeps the R4 dataflow (A uniform -> s_load; B coalesced
// from L2; spatial SREG=4) but splits K 8-ways: 512-thread blocks, 8 waves,
// 7200 total waves ~ 6-7/SIMD. Each wave: 4 c/phase = 4 B global_dwordx4 +
// 4 A s_load_dwordx16 (one per position) + 96 pk-FMA. Combine: 3-level LDS
// tree (32KB) with barriers only after the main loop.

typedef float v2f __attribute__((ext_vector_type(2)));

#define BB   4
#define CC   32
#define HH   32
#define WW   32
#define OO   64
#define HO   30
#define WO   30
#define NSP  (HO*WO)   // 900 = 4*225, no tail

// ---- prep: A[b,h,w,c] = (mp, mn, mp*log mp, mn*log mn)
//            Bm[ij,c,o] = (e^k1, k1*e^k1, e^k2, k2*e^k2)
__global__ __launch_bounds__(256) void smorph_prep(
    const float* __restrict__ x, const float* __restrict__ k1,
    const float* __restrict__ k2, float4* __restrict__ A, float4* __restrict__ Bm)
{
    int t = blockIdx.x * 256 + threadIdx.x;
    if (t < BB*CC*HH*WW) {
        float v = x[t];
        int b = t >> 15, c = (t >> 10) & 31, h = (t >> 5) & 31, w = t & 31;
        float mp = fmaxf(v, 0.1f), mn = fmaxf(-v, 0.1f);
        A[((b*HH + h)*WW + w)*CC + c] =
            make_float4(mp, mn, mp*logf(mp), mn*logf(mn));
    }
    if (t < 9*CC*OO) {
        float a = k1[t], bb = k2[t];
        float e1 = expf(a), e2 = expf(bb);
        Bm[t] = make_float4(e1, a*e1, e2, bb*e2);
    }
}

__global__ __launch_bounds__(512, 6) void smorph_main(
    const float4* __restrict__ A, const float4* __restrict__ Bm,
    const float* __restrict__ bias, float* __restrict__ out)
{
    __shared__ v2f ldsr[4*16*64];   // 32 KB combine scratch (used only at end)

    const int tid = threadIdx.x;
    const int o   = tid & 63;
    const int kq  = __builtin_amdgcn_readfirstlane(tid >> 6);  // wave 0..7, c-range [4kq,4kq+4)
    const int b   = blockIdx.y;
    const int s0  = blockIdx.x * 4;

    int abase[4];                   // float4 index of pixel (b,ho,wo), c = kq*4 (uniform)
#pragma unroll
    for (int t = 0; t < 4; ++t) {
        int s = s0 + t;
        int ho = s / WO, wo = s - ho*WO;
        abase[t] = ((b*HH + ho)*WW + wo)*CC + kq*4;
    }

    v2f P1d[4] = {}, P1n[4] = {}, P2d[4] = {}, P2n[4] = {};

    const float4* Bq = Bm + kq*4*OO + o;     // lane-coalesced B base

#pragma unroll
    for (int ij = 0; ij < 9; ++ij) {
        const int i = ij/3, j = ij - 3*(ij/3);

        float4 Bv[4];                        // 4x global_load_dwordx4, L2-hit
#pragma unroll
        for (int c = 0; c < 4; ++c) Bv[c] = Bq[ij*(CC*OO) + c*OO];

#pragma unroll
        for (int t = 0; t < 4; ++t) {
            const float4* Ap = A + (abase[t] + (i*WW + j)*CC);  // uniform: s_load_dwordx16
#pragma unroll
            for (int c = 0; c < 4; ++c) {
                float4 Av = Ap[c];
                v2f a1 = {Av.x, Av.y};       // (mp, mn)
                v2f a2 = {Av.z, Av.w};       // (mp*lmp, mn*lmn)
                v2f be1 = {Bv[c].x, Bv[c].x}, bk1 = {Bv[c].y, Bv[c].y};
                v2f be2 = {Bv[c].z, Bv[c].z}, bk2 = {Bv[c].w, Bv[c].w};
                P1d[t] += a1 * be1;
                P1n[t] += a2 * be1;
                P1n[t] += a1 * bk1;
                P2d[t] += a1 * be2;
                P2n[t] += a2 * be2;
                P2n[t] += a1 * bk2;
            }
        }
    }

    // ---- combine K-split partials across 8 waves: 3-level LDS tree
    // level 1: waves 4..7 -> slots 0..3; waves 0..3 add
    if (kq >= 4) {
        v2f* dst = ldsr + (kq - 4)*1024 + o;
#pragma unroll
        for (int t = 0; t < 4; ++t) {
            dst[(t*4+0)*64] = P1d[t];
            dst[(t*4+1)*64] = P1n[t];
            dst[(t*4+2)*64] = P2d[t];
            dst[(t*4+3)*64] = P2n[t];
        }
    }
    __syncthreads();
    if (kq < 4) {
        const v2f* srcp = ldsr + kq*1024 + o;
#pragma unroll
        for (int t = 0; t < 4; ++t) {
            P1d[t] += srcp[(t*4+0)*64];
            P1n[t] += srcp[(t*4+1)*64];
            P2d[t] += srcp[(t*4+2)*64];
            P2n[t] += srcp[(t*4+3)*64];
        }
    }
    __syncthreads();
    // level 2: waves 2,3 -> slots 0,1; waves 0,1 add
    if (kq == 2 || kq == 3) {
        v2f* dst = ldsr + (kq - 2)*1024 + o;
#pragma unroll
        for (int t = 0; t < 4; ++t) {
            dst[(t*4+0)*64] = P1d[t];
            dst[(t*4+1)*64] = P1n[t];
            dst[(t*4+2)*64] = P2d[t];
            dst[(t*4+3)*64] = P2n[t];
        }
    }
    __syncthreads();
    if (kq < 2) {
        const v2f* srcp = ldsr + kq*1024 + o;
#pragma unroll
        for (int t = 0; t < 4; ++t) {
            P1d[t] += srcp[(t*4+0)*64];
            P1n[t] += srcp[(t*4+1)*64];
            P2d[t] += srcp[(t*4+2)*64];
            P2n[t] += srcp[(t*4+3)*64];
        }
    }
    __syncthreads();
    // level 3: wave 1 -> slot 0; wave 0 finishes
    if (kq == 1) {
        v2f* dst = ldsr + o;
#pragma unroll
        for (int t = 0; t < 4; ++t) {
            dst[(t*4+0)*64] = P1d[t];
            dst[(t*4+1)*64] = P1n[t];
            dst[(t*4+2)*64] = P2d[t];
            dst[(t*4+3)*64] = P2n[t];
        }
    }
    __syncthreads();
    if (kq == 0) {
        const v2f* srcp = ldsr + o;
        const float bo = bias[o];
#pragma unroll
        for (int t = 0; t < 4; ++t) {
            v2f d1 = P1d[t] + srcp[(t*4+0)*64];
            v2f n1 = P1n[t] + srcp[(t*4+1)*64];
            v2f d2 = P2d[t] + srcp[(t*4+2)*64];
            v2f n2 = P2n[t] + srcp[(t*4+3)*64];
            float r = expf(n1.x/d1.x) - expf(n2.x/d2.x)
                    - expf(n1.y/d1.y) + expf(n2.y/d2.y) + bo;
            out[(size_t)(b*OO + o)*NSP + (s0 + t)] = r;
        }
    }
}

extern "C" void kernel_launch(void* const* d_in, const int* in_sizes, int n_in,
                              void* d_out, int out_size, void* d_ws, size_t ws_size,
                              hipStream_t stream) {
    const float* x    = (const float*)d_in[0];
    const float* k1   = (const float*)d_in[1];
    const float* k2   = (const float*)d_in[2];
    const float* bias = (const float*)d_in[3];

    float4* A  = (float4*)d_ws;                                   // 2 MB
    float4* Bm = (float4*)((char*)d_ws + (size_t)BB*HH*WW*CC*16); // 294 KB
    float*  out = (float*)d_out;

    hipLaunchKernelGGL(smorph_prep, dim3((BB*CC*HH*WW + 255)/256), dim3(256), 0, stream,
                       x, k1, k2, A, Bm);

    hipLaunchKernelGGL(smorph_main, dim3(NSP/4, BB), dim3(512), 0, stream,
                       A, Bm, bias, out);
}